// Round 7
// baseline (90.216 us; speedup 1.0000x reference)
//
#include <hip/hip_runtime.h>

#define NJ 8
#define TS 2048
#define NB 1024
#define CHUNK 128               // 64 lanes * 2 steps per wave-scan
#define NCH (TS / CHUNK)        // 16
#define F4C (CHUNK * NJ)        // 1024 float4 = 16 KB per buffer
#define DTC (1.0f / 60.0f)

// async global->LDS, 16B per lane. lds_base must be wave-uniform; HW writes
// lds_base + lane*16. Global src is per-lane.
__device__ __forceinline__ void dma16(const float4* g, float4* lds_base) {
#if __has_builtin(__builtin_amdgcn_global_load_lds)
    __builtin_amdgcn_global_load_lds(
        (const __attribute__((address_space(1))) void*)g,
        (__attribute__((address_space(3))) void*)lds_base,
        16, 0, 0);
#else
    lds_base[threadIdx.x & 63] = *g;
#endif
}

__global__ __launch_bounds__(512, 8) void phys_pipe2_kernel(
    const float4* __restrict__ x,       // (B,T,8) as float4 per (t,joint)
    const float*  __restrict__ state0,  // (B,8,2)
    const float*  __restrict__ M,       // (8,2)
    const float*  __restrict__ inertia, // (8,)
    const float*  __restrict__ damping, // (8,)
    float* __restrict__ out,            // (B,T,8)
    float* __restrict__ muscle,         // (B,8,2,2)
    float* __restrict__ finals)         // (B,8,2)
{
    __shared__ float4 xin[2][F4C];           // 2 x 16 KB input double-buffer
    __shared__ float4 tb[2][CHUNK * NJ / 4]; // 2 x 4 KB theta transpose dbuf

    const int b    = blockIdx.x;
    const int tid  = threadIdx.x;
    const int j    = tid >> 6;          // wave id = joint index
    const int lane = tid & 63;

    const float M0  = M[j * 2 + 0];
    const float M1  = M[j * 2 + 1];
    const float M20 = M0 * M0;
    const float M21 = M1 * M1;
    const float d   = damping[j];
    const float p   = DTC / inertia[j];      // DT / I
    const float g   = 1.0f - p * d;          // dθ self-coefficient

    float thc  = state0[(b * NJ + j) * 2 + 0];
    float dthc = state0[(b * NJ + j) * 2 + 1];

    const float4* xb = x + (size_t)b * TS * NJ;
    const int wv = j;   // wave index == joint

    // xin swizzle: sigma(i) = i ^ ((i>>4)&7) (involution; mask bits 4-6
    // XOR bits 0-2). DMA dest is linear (512i + 64w + lane); global src is
    // pre-swizzled: src = dest ^ ((dest>>4)&7) = dest with lane ^ ((4w+(lane>>4))&7).
    const int slane = lane ^ ((4 * wv + (lane >> 4)) & 7);

    // prologue: async-stage chunk 0
    {
        float4* lb = &xin[0][64 * wv];
        const float4* gb = xb + 64 * wv + slane;
        #pragma unroll
        for (int i = 0; i < 2; ++i) dma16(gb + 512 * i, lb + 512 * i);
    }

    for (int ch = 0; ch <= NCH; ++ch) {
        // single barrier per chunk: drains DMA(ch) [vmcnt] and makes
        // tout(ch-1) visible [lgkmcnt]; also buffer-overwrite safety.
        __syncthreads();

        // issue DMA for chunk ch+1 into the other xin buffer (full-chunk slack)
        if (ch + 1 < NCH) {
            float4* lb = &xin[(ch + 1) & 1][64 * wv];
            const float4* gb = xb + (size_t)(ch + 1) * F4C + 64 * wv + slane;
            #pragma unroll
            for (int i = 0; i < 2; ++i) dma16(gb + 512 * i, lb + 512 * i);
        }

        // ---- store phase: coalesced write-out of chunk ch-1's theta ----
        // tout word w stored at w ^ ((w>>5)&31). For out-float4 f (words
        // 4f+c): mask m = (f>>3)&31 (uniform over c); block q = f ^ (m>>2)
        // = f ^ ((f>>5)&7); component permute pm = m&3 = (f>>3)&3.
        if (ch > 0 && tid < 256) {
            const float4* tr = tb[(ch - 1) & 1];
            float* outc = out + ((size_t)b * TS + (size_t)(ch - 1) * CHUNK) * NJ;
            int f  = tid;
            int q  = f ^ ((f >> 5) & 7);
            int pm = (f >> 3) & 3;
            float4 r = tr[q];
            float rx = r.x, ry = r.y, rz = r.z, rw = r.w;
            if (pm & 1) { float tq = rx; rx = ry; ry = tq; tq = rz; rz = rw; rw = tq; }
            if (pm & 2) { float tq = rx; rx = rz; rz = tq; tq = ry; ry = rw; rw = tq; }
            ((float4*)outc)[f] = make_float4(rx, ry, rz, rw);
        }

        if (ch < NCH) {
            // ---- compute phase on xin[ch&1] ----
            const float4* xc = xin[ch & 1];
            float* tw = (float*)tb[ch & 1];

            // element (step s=2*lane+k, joint j): natural idx 16*lane+8k+j,
            // swizzled ^((idx>>4)&7) = ^(lane&7)  -> 2-way on b128 read (free)
            float a[2], c[2];
            const int base = 16 * lane + (j ^ (lane & 7));
            #pragma unroll
            for (int k = 0; k < 2; ++k) {
                float4 v = xc[base + 8 * k];
                a[k] = fmaf(M0,  v.x, M1  * v.y);   // einsum(M, F_t)
                c[k] = fmaf(M20, v.z, M21 * v.w);   // einsum(M2, K_t)
            }

            // serially compose my 2 step-maps:
            //   dθ' = r0·θ + r1·dθ + rc ;  θ' = s0·θ + s1·dθ + sc
            float r0 = 0.0f, r1 = 1.0f, rc = 0.0f;   // identity
            float s0 = 1.0f, s1 = 0.0f, sc = 0.0f;
            #pragma unroll
            for (int k = 0; k < 2; ++k) {
                float pa = p * a[k];
                float pc = p * c[k];
                float nr0 = fmaf(-pc, s0, g * r0);
                float nr1 = fmaf(-pc, s1, g * r1);
                float nrc = fmaf(-pc, sc, fmaf(g, rc, pa));
                s0 = fmaf(DTC, nr0, s0);
                s1 = fmaf(DTC, nr1, s1);
                sc = fmaf(DTC, nrc, sc);
                r0 = nr0; r1 = nr1; rc = nrc;
            }

            // inclusive Kogge-Stone over 64 lanes (compose: mine ∘ other)
            #pragma unroll
            for (int delta = 1; delta < 64; delta <<= 1) {
                float o_r0 = __shfl_up(r0, delta, 64);
                float o_r1 = __shfl_up(r1, delta, 64);
                float o_rc = __shfl_up(rc, delta, 64);
                float o_s0 = __shfl_up(s0, delta, 64);
                float o_s1 = __shfl_up(s1, delta, 64);
                float o_sc = __shfl_up(sc, delta, 64);
                if (lane >= delta) {
                    float nr0 = fmaf(r0, o_s0, r1 * o_r0);
                    float nr1 = fmaf(r0, o_s1, r1 * o_r1);
                    float nrc = fmaf(r0, o_sc, fmaf(r1, o_rc, rc));
                    float ns0 = fmaf(s0, o_s0, s1 * o_r0);
                    float ns1 = fmaf(s0, o_s1, s1 * o_r1);
                    float nsc = fmaf(s0, o_sc, fmaf(s1, o_rc, sc));
                    r0 = nr0; r1 = nr1; rc = nrc;
                    s0 = ns0; s1 = ns1; sc = nsc;
                }
            }

            // exclusive prefix: lane l uses inclusive result of lane l-1
            float e_r0 = __shfl_up(r0, 1, 64);
            float e_r1 = __shfl_up(r1, 1, 64);
            float e_rc = __shfl_up(rc, 1, 64);
            float e_s0 = __shfl_up(s0, 1, 64);
            float e_s1 = __shfl_up(s1, 1, 64);
            float e_sc = __shfl_up(sc, 1, 64);
            if (lane == 0) {
                e_r0 = 0.0f; e_r1 = 1.0f; e_rc = 0.0f;
                e_s0 = 1.0f; e_s1 = 0.0f; e_sc = 0.0f;
            }

            // state at my first step
            float th  = fmaf(e_s0, thc, fmaf(e_s1, dthc, e_sc));
            float dth = fmaf(e_r0, thc, fmaf(e_r1, dthc, e_rc));

            // replay 2 steps in exact reference op-order; θ -> transpose buf.
            // word w = 16*lane+8k+j; store at w ^ ((w>>5)&31) = w ^ ((lane>>1)&31)
            const int wsig = (lane >> 1) & 31;
            #pragma unroll
            for (int k = 0; k < 2; ++k) {
                float u = fmaf(-c[k], th, a[k]);     // a - c·θ
                u = fmaf(-d, dth, u);                // ... - d·dθ
                dth = fmaf(p, u, dth);
                th  = fmaf(DTC, dth, th);
                tw[(16 * lane + 8 * k + j) ^ wsig] = th;
            }

            // carry = lane 63's end state
            thc  = __shfl(th, 63, 64);
            dthc = __shfl(dth, 63, 64);
        }
    }

    if (lane == 0) {
        const int idx = b * NJ + j;
        finals[idx * 2 + 0] = thc;
        finals[idx * 2 + 1] = dthc;
        muscle[idx * 4 + 0] = thc  * M0;
        muscle[idx * 4 + 1] = thc  * M1;
        muscle[idx * 4 + 2] = dthc * M0;
        muscle[idx * 4 + 3] = dthc * M1;
    }
}

extern "C" void kernel_launch(void* const* d_in, const int* in_sizes, int n_in,
                              void* d_out, int out_size, void* d_ws, size_t ws_size,
                              hipStream_t stream) {
    const float4* x      = (const float4*)d_in[0];
    const float*  state0 = (const float*)d_in[1];
    const float*  M      = (const float*)d_in[2];
    const float*  inertia= (const float*)d_in[3];
    const float*  damping= (const float*)d_in[4];

    float* out    = (float*)d_out;                       // (B,T,8)
    float* muscle = out + (size_t)NB * TS * NJ;          // (B,8,2,2)
    float* finals = muscle + (size_t)NB * NJ * 2 * 2;    // (B,8,2)

    dim3 block(512);          // 8 waves = 8 joints of one batch
    dim3 grid(NB);
    phys_pipe2_kernel<<<grid, block, 0, stream>>>(x, state0, M, inertia, damping,
                                                  out, muscle, finals);
}

// Round 8
// 82.070 us; speedup vs baseline: 1.0993x; 1.0993x over previous
//
#include <hip/hip_runtime.h>

#define NJ 8
#define TS 2048
#define NB 1024
#define JW 4                    // joints per wave (lane = 4*s + jl)
#define SEG 16                  // time-segments per wave (s = lane>>2)
#define RST 8                   // steps per lane
#define CHUNK (SEG*RST)         // 128 steps per chunk
#define NCH (TS/CHUNK)          // 16
#define F4W (CHUNK*JW)          // 512 float4 = 8 KB per wave-buffer
#define DTC (1.0f/60.0f)

// async global->LDS, 16B/lane. lds_base wave-uniform; HW writes base+lane*16.
__device__ __forceinline__ void dma16(const float4* g, float4* lds_base) {
    __builtin_amdgcn_global_load_lds(
        (const __attribute__((address_space(1))) void*)g,
        (__attribute__((address_space(3))) void*)lds_base, 16, 0, 0);
}

__global__ __launch_bounds__(256) void phys_async_kernel(
    const float4* __restrict__ x,       // (B,T,8) as float4 per (t,joint)
    const float*  __restrict__ state0,  // (B,8,2)
    const float*  __restrict__ M,       // (8,2)
    const float*  __restrict__ inertia, // (8,)
    const float*  __restrict__ damping, // (8,)
    float* __restrict__ out,            // (B,T,8)
    float* __restrict__ muscle,         // (B,8,2,2)
    float* __restrict__ finals)         // (B,8,2)
{
    __shared__ float4 buf[4][2][F4W];   // 4 waves x 2 bufs x 8 KB = 64 KB

    const int tid  = threadIdx.x;
    const int w    = tid >> 6;          // wave in block
    const int lane = tid & 63;
    const int gw   = blockIdx.x * 4 + w;    // 0..2047
    const int b    = gw >> 1;               // batch
    const int J0   = (gw & 1) * JW;         // joint half: 0 or 4
    const int s    = lane >> 2;             // time-segment 0..15
    const int jl   = lane & 3;              // joint-in-half 0..3
    const int j    = J0 + jl;

    const float M0  = M[j*2+0];
    const float M1  = M[j*2+1];
    const float M20 = M0*M0, M21 = M1*M1;
    const float dmp = damping[j];
    const float p   = DTC / inertia[j];
    const float gd  = 1.0f - p * dmp;

    float thc  = state0[(b*NJ+j)*2+0];
    float dthc = state0[(b*NJ+j)*2+1];

    const float4* xb = x + (size_t)b * TS * NJ;

    float4* bufA = buf[w][0];
    float4* bufB = buf[w][1];

    // drain param loads so the counted-vmcnt protocol starts from 0
    asm volatile("s_waitcnt vmcnt(0)" ::: "memory");
    __builtin_amdgcn_sched_barrier(0);

    // DMA one chunk into bb. LDS dest linear d = 64i+lane; natural element
    // n = sigma(d) = d ^ ((d>>4)&7) (involution). Natural n = 4*t_local + jl_n.
    // Global float4 idx = 8*(T0 + (n>>2)) + J0 + (n&3). Each instr covers 16
    // full 64B lines (J0-half of 16 rows) -> fully coalesced.
    auto issue = [&](int ch, float4* bb) {
        const int T0 = ch * CHUNK;
        #pragma unroll
        for (int i = 0; i < 8; ++i) {
            int d = 64*i + lane;
            int n = d ^ ((d >> 4) & 7);
            const float4* src = xb + (size_t)(T0 + (n >> 2)) * NJ + J0 + (n & 3);
            dma16(src, bb + 64*i);
        }
    };

    // prologue: chunks 0,1 in flight (8+8 vmem ops)
    issue(0, bufA);
    issue(1, bufB);

    float4* cur = bufA;
    float4* nxt = bufB;

    for (int ch = 0; ch < NCH; ++ch) {
        // counted wait: ensure DMA(ch) complete, keep younger ops in flight.
        // per-iter vmem ops in order: DMA(ch+2) x8, stores(ch) x8.
        // younger-than-DMA(ch): steady = S(ch-2)+D(ch+1)+S(ch-1) = 24;
        // ch==0: D(1)=8; ch==1: D(2)+S(0)=16; ch==NCH-1: S(NCH-3)+S(NCH-2)=16.
        if (ch == 0)          { asm volatile("s_waitcnt vmcnt(8)"  ::: "memory"); }
        else if (ch == 1)     { asm volatile("s_waitcnt vmcnt(16)" ::: "memory"); }
        else if (ch == NCH-1) { asm volatile("s_waitcnt vmcnt(16)" ::: "memory"); }
        else                  { asm volatile("s_waitcnt vmcnt(24)" ::: "memory"); }
        __builtin_amdgcn_sched_barrier(0);

        // read my 8 steps (t_local = 8s+k): natural n = 32s+4k+jl, read at
        // sigma(n) = n ^ ((n>>4)&7)  (balanced 8 lanes/bank-group)
        float a[RST], cc[RST];
        #pragma unroll
        for (int k = 0; k < RST; ++k) {
            int n  = 32*s + 4*k + jl;
            int ri = n ^ ((n >> 4) & 7);
            float4 v = cur[ri];
            a[k]  = fmaf(M0,  v.x, M1  * v.y);   // einsum(M, F_t)
            cc[k] = fmaf(M20, v.z, M21 * v.w);   // einsum(M2, K_t)
        }
        // reads complete before DMA may overwrite this buffer
        asm volatile("s_waitcnt lgkmcnt(0)" ::: "memory");
        __builtin_amdgcn_sched_barrier(0);

        if (ch + 2 < NCH) issue(ch + 2, cur);
        __builtin_amdgcn_sched_barrier(0);

        // serially compose my 8 step-maps:
        //   dθ' = r0·θ + r1·dθ + rc ;  θ' = s0·θ + s1·dθ + sc
        float r0 = 0.0f, r1 = 1.0f, rc = 0.0f;
        float s0 = 1.0f, s1 = 0.0f, sc = 0.0f;
        #pragma unroll
        for (int k = 0; k < RST; ++k) {
            float pa = p * a[k];
            float pc = p * cc[k];
            float nr0 = fmaf(-pc, s0, gd * r0);
            float nr1 = fmaf(-pc, s1, gd * r1);
            float nrc = fmaf(-pc, sc, fmaf(gd, rc, pa));
            s0 = fmaf(DTC, nr0, s0);
            s1 = fmaf(DTC, nr1, s1);
            sc = fmaf(DTC, nrc, sc);
            r0 = nr0; r1 = nr1; rc = nrc;
        }

        // Kogge-Stone over 16 segments (lane stride 4): 4 rounds
        #pragma unroll
        for (int dl = 4; dl < 64; dl <<= 1) {
            float o_r0 = __shfl_up(r0, dl, 64);
            float o_r1 = __shfl_up(r1, dl, 64);
            float o_rc = __shfl_up(rc, dl, 64);
            float o_s0 = __shfl_up(s0, dl, 64);
            float o_s1 = __shfl_up(s1, dl, 64);
            float o_sc = __shfl_up(sc, dl, 64);
            if (lane >= dl) {
                float nr0 = fmaf(r0, o_s0, r1 * o_r0);
                float nr1 = fmaf(r0, o_s1, r1 * o_r1);
                float nrc = fmaf(r0, o_sc, fmaf(r1, o_rc, rc));
                float ns0 = fmaf(s0, o_s0, s1 * o_r0);
                float ns1 = fmaf(s0, o_s1, s1 * o_r1);
                float nsc = fmaf(s0, o_sc, fmaf(s1, o_rc, sc));
                r0 = nr0; r1 = nr1; rc = nrc;
                s0 = ns0; s1 = ns1; sc = nsc;
            }
        }

        // exclusive prefix: segment s uses inclusive result of segment s-1
        float e_r0 = __shfl_up(r0, 4, 64);
        float e_r1 = __shfl_up(r1, 4, 64);
        float e_rc = __shfl_up(rc, 4, 64);
        float e_s0 = __shfl_up(s0, 4, 64);
        float e_s1 = __shfl_up(s1, 4, 64);
        float e_sc = __shfl_up(sc, 4, 64);
        if (lane < 4) {
            e_r0 = 0.0f; e_r1 = 1.0f; e_rc = 0.0f;
            e_s0 = 1.0f; e_s1 = 0.0f; e_sc = 0.0f;
        }

        // state at my first step
        float th  = fmaf(e_s0, thc, fmaf(e_s1, dthc, e_sc));
        float dth = fmaf(e_r0, thc, fmaf(e_r1, dthc, e_rc));

        // replay 8 steps in exact reference op-order; stores are lane-linear
        // coalesced: word = 8*(T0+8s+k) + j
        float* outp = out + ((size_t)b * TS + (size_t)ch * CHUNK + RST*s) * NJ + j;
        #pragma unroll
        for (int k = 0; k < RST; ++k) {
            float u = fmaf(-cc[k], th, a[k]);    // a - c·θ
            u = fmaf(-dmp, dth, u);              // ... - d·dθ
            dth = fmaf(p, u, dth);
            th  = fmaf(DTC, dth, th);
            outp[k*NJ] = th;
        }

        // carry for my joint = end state of segment 15 (lane 60+jl)
        thc  = __shfl(th,  60 + jl, 64);
        dthc = __shfl(dth, 60 + jl, 64);

        float4* t = cur; cur = nxt; nxt = t;
    }

    if (lane < 4) {
        const int idx = b * NJ + J0 + jl;
        finals[idx*2+0] = thc;
        finals[idx*2+1] = dthc;
        muscle[idx*4+0] = thc  * M0;
        muscle[idx*4+1] = thc  * M1;
        muscle[idx*4+2] = dthc * M0;
        muscle[idx*4+3] = dthc * M1;
    }
}

extern "C" void kernel_launch(void* const* d_in, const int* in_sizes, int n_in,
                              void* d_out, int out_size, void* d_ws, size_t ws_size,
                              hipStream_t stream) {
    const float4* x      = (const float4*)d_in[0];
    const float*  state0 = (const float*)d_in[1];
    const float*  M      = (const float*)d_in[2];
    const float*  inertia= (const float*)d_in[3];
    const float*  damping= (const float*)d_in[4];

    float* out    = (float*)d_out;                       // (B,T,8)
    float* muscle = out + (size_t)NB * TS * NJ;          // (B,8,2,2)
    float* finals = muscle + (size_t)NB * NJ * 2 * 2;    // (B,8,2)

    dim3 block(256);          // 4 waves; each wave = 1 batch-half, independent
    dim3 grid(NB * 2 / 4);    // 512 blocks = 2048 waves
    phys_async_kernel<<<grid, block, 0, stream>>>(x, state0, M, inertia, damping,
                                                  out, muscle, finals);
}

// Round 9
// 73.421 us; speedup vs baseline: 1.2287x; 1.1178x over previous
//
#include <hip/hip_runtime.h>

#define NJ 8
#define TS 2048
#define NB 1024
#define JW 4                    // joints per half-block
#define CHUNK 256               // 64 lanes * 4 steps per wave-scan
#define NCH (TS / CHUNK)        // 8
#define F4C (CHUNK * JW)        // 1024 float4 = 16 KB per buffer
#define DTC (1.0f / 60.0f)

// async global->LDS, 16B per lane. lds_base must be wave-uniform; HW writes
// lds_base + lane*16. Global src is per-lane.
__device__ __forceinline__ void dma16(const float4* g, float4* lds_base) {
#if __has_builtin(__builtin_amdgcn_global_load_lds)
    __builtin_amdgcn_global_load_lds(
        (const __attribute__((address_space(1))) void*)g,
        (__attribute__((address_space(3))) void*)lds_base,
        16, 0, 0);
#else
    lds_base[threadIdx.x & 63] = *g;
#endif
}

__global__ __launch_bounds__(256, 4) void phys_half_kernel(
    const float4* __restrict__ x,       // (B,T,8) as float4 per (t,joint)
    const float*  __restrict__ state0,  // (B,8,2)
    const float*  __restrict__ M,       // (8,2)
    const float*  __restrict__ inertia, // (8,)
    const float*  __restrict__ damping, // (8,)
    float* __restrict__ out,            // (B,T,8)
    float* __restrict__ muscle,         // (B,8,2,2)
    float* __restrict__ finals)         // (B,8,2)
{
    __shared__ float4 xin[2][F4C];           // 2 x 16 KB input double-buffer
    __shared__ float4 tb[2][CHUNK * JW / 4]; // 2 x 4 KB theta transpose dbuf

    // sibling half-blocks (same batch) differ by 8 in blockIdx -> same XCD
    // (id%8 equal), dispatched back-to-back -> partial output lines merge in
    // the shared per-XCD L2; x-reads share fetched lines.
    const int g   = blockIdx.x;
    const int b   = (g & 7) | ((g >> 4) << 3);
    const int J0  = ((g >> 3) & 1) * JW;

    const int tid  = threadIdx.x;
    const int w    = tid >> 6;          // wave id = joint offset in half
    const int lane = tid & 63;
    const int j    = J0 + w;

    const float M0  = M[j * 2 + 0];
    const float M1  = M[j * 2 + 1];
    const float M20 = M0 * M0;
    const float M21 = M1 * M1;
    const float d   = damping[j];
    const float p   = DTC / inertia[j];      // DT / I
    const float gd  = 1.0f - p * d;          // dθ self-coefficient

    float thc  = state0[(b * NJ + j) * 2 + 0];
    float dthc = state0[(b * NJ + j) * 2 + 1];

    const float4* xb = x + (size_t)b * TS * NJ;

    // xin layout: natural n = 4*t_local + jl; stored at sigma(n) = n^((n>>4)&7)
    // (involution: XOR bits4-6 into bits0-2). DMA dest linear d = 256w+64i+lane,
    // global element n = sigma(d): t_local = n>>2, jl = n&3. Each dma16 covers
    // 16 consecutive steps x 4 joints = 16 full 64-B half-rows (dense).
    auto issue = [&](int ch, float4* bb) {
        const int T0 = ch * CHUNK;
        #pragma unroll
        for (int i = 0; i < 4; ++i) {
            int dd = 256 * w + 64 * i + lane;
            int n  = dd ^ ((dd >> 4) & 7);
            const float4* src = xb + (size_t)(T0 + (n >> 2)) * NJ + J0 + (n & 3);
            dma16(src, bb + 256 * w + 64 * i);
        }
    };

    // prologue: async-stage chunk 0
    issue(0, xin[0]);

    for (int ch = 0; ch <= NCH; ++ch) {
        // single barrier per chunk: drains DMA(ch) [vmcnt] and makes
        // tout(ch-1) visible [lgkmcnt]; also buffer-overwrite safety.
        __syncthreads();

        // issue DMA for chunk ch+1 into the other xin buffer (full-chunk slack)
        if (ch + 1 < NCH) issue(ch + 1, xin[(ch + 1) & 1]);

        // ---- store phase: coalesced write-out of chunk ch-1's theta ----
        // word (4f+c) stored at (4f+c)^m, m=(f>>3)&31 -> b128 block f^(m>>2),
        // components permuted by pm=m&3.
        if (ch > 0) {
            const float4* tr = tb[(ch - 1) & 1];
            int f  = tid;                       // 0..255
            int q  = f ^ ((f >> 5) & 7);
            int pm = (f >> 3) & 3;
            float4 r = tr[q];
            float rx = r.x, ry = r.y, rz = r.z, rw = r.w;
            if (pm & 1) { float tq = rx; rx = ry; ry = tq; tq = rz; rz = rw; rw = tq; }
            if (pm & 2) { float tq = rx; rx = rz; rz = tq; tq = ry; ry = rw; rw = tq; }
            float4* og = (float4*)out
                       + 2 * ((size_t)b * TS + (size_t)(ch - 1) * CHUNK + f)
                       + (J0 >> 2);
            *og = make_float4(rx, ry, rz, rw);
        }

        if (ch < NCH) {
            // ---- compute phase on xin[ch&1] ----
            const float4* xc = xin[ch & 1];
            float* tw = (float*)tb[ch & 1];

            // element (step 4*lane+k, joint w): natural n = 16*lane + 4k + w,
            // read at n ^ ((n>>4)&7) = n ^ (lane&7)  -> conflict-free b128
            float a[4], cc[4];
            const int bm = lane & 7;
            #pragma unroll
            for (int k = 0; k < 4; ++k) {
                int n = 16 * lane + 4 * k + w;
                float4 v = xc[n ^ bm];
                a[k]  = fmaf(M0,  v.x, M1  * v.y);   // einsum(M, F_t)
                cc[k] = fmaf(M20, v.z, M21 * v.w);   // einsum(M2, K_t)
            }

            // serially compose my 4 step-maps:
            //   dθ' = r0·θ + r1·dθ + rc ;  θ' = s0·θ + s1·dθ + sc
            float r0 = 0.0f, r1 = 1.0f, rc = 0.0f;   // identity
            float s0 = 1.0f, s1 = 0.0f, sc = 0.0f;
            #pragma unroll
            for (int k = 0; k < 4; ++k) {
                float pa = p * a[k];
                float pc = p * cc[k];
                float nr0 = fmaf(-pc, s0, gd * r0);
                float nr1 = fmaf(-pc, s1, gd * r1);
                float nrc = fmaf(-pc, sc, fmaf(gd, rc, pa));
                s0 = fmaf(DTC, nr0, s0);
                s1 = fmaf(DTC, nr1, s1);
                sc = fmaf(DTC, nrc, sc);
                r0 = nr0; r1 = nr1; rc = nrc;
            }

            // inclusive Kogge-Stone over 64 lanes (compose: mine ∘ other)
            #pragma unroll
            for (int delta = 1; delta < 64; delta <<= 1) {
                float o_r0 = __shfl_up(r0, delta, 64);
                float o_r1 = __shfl_up(r1, delta, 64);
                float o_rc = __shfl_up(rc, delta, 64);
                float o_s0 = __shfl_up(s0, delta, 64);
                float o_s1 = __shfl_up(s1, delta, 64);
                float o_sc = __shfl_up(sc, delta, 64);
                if (lane >= delta) {
                    float nr0 = fmaf(r0, o_s0, r1 * o_r0);
                    float nr1 = fmaf(r0, o_s1, r1 * o_r1);
                    float nrc = fmaf(r0, o_sc, fmaf(r1, o_rc, rc));
                    float ns0 = fmaf(s0, o_s0, s1 * o_r0);
                    float ns1 = fmaf(s0, o_s1, s1 * o_r1);
                    float nsc = fmaf(s0, o_sc, fmaf(s1, o_rc, sc));
                    r0 = nr0; r1 = nr1; rc = nrc;
                    s0 = ns0; s1 = ns1; sc = nsc;
                }
            }

            // exclusive prefix: lane l uses inclusive result of lane l-1
            float e_r0 = __shfl_up(r0, 1, 64);
            float e_r1 = __shfl_up(r1, 1, 64);
            float e_rc = __shfl_up(rc, 1, 64);
            float e_s0 = __shfl_up(s0, 1, 64);
            float e_s1 = __shfl_up(s1, 1, 64);
            float e_sc = __shfl_up(sc, 1, 64);
            if (lane == 0) {
                e_r0 = 0.0f; e_r1 = 1.0f; e_rc = 0.0f;
                e_s0 = 1.0f; e_s1 = 0.0f; e_sc = 0.0f;
            }

            // state at my first step
            float th  = fmaf(e_s0, thc, fmaf(e_s1, dthc, e_sc));
            float dth = fmaf(e_r0, thc, fmaf(e_r1, dthc, e_rc));

            // replay 4 steps in exact reference op-order; θ -> transpose buf.
            // word wd = 16*lane + 4k + w; store at wd ^ ((wd>>5)&31)
            //         = wd ^ ((lane>>1)&31)   (2 lanes/bank = free)
            const int wsig = (lane >> 1) & 31;
            #pragma unroll
            for (int k = 0; k < 4; ++k) {
                float u = fmaf(-cc[k], th, a[k]);    // a - c·θ
                u = fmaf(-d, dth, u);                // ... - d·dθ
                dth = fmaf(p, u, dth);
                th  = fmaf(DTC, dth, th);
                tw[(16 * lane + 4 * k + w) ^ wsig] = th;
            }

            // carry = lane 63's end state
            thc  = __shfl(th, 63, 64);
            dthc = __shfl(dth, 63, 64);
        }
    }

    if (lane == 0) {
        const int idx = b * NJ + j;
        finals[idx * 2 + 0] = thc;
        finals[idx * 2 + 1] = dthc;
        muscle[idx * 4 + 0] = thc  * M0;
        muscle[idx * 4 + 1] = thc  * M1;
        muscle[idx * 4 + 2] = dthc * M0;
        muscle[idx * 4 + 3] = dthc * M1;
    }
}

extern "C" void kernel_launch(void* const* d_in, const int* in_sizes, int n_in,
                              void* d_out, int out_size, void* d_ws, size_t ws_size,
                              hipStream_t stream) {
    const float4* x      = (const float4*)d_in[0];
    const float*  state0 = (const float*)d_in[1];
    const float*  M      = (const float*)d_in[2];
    const float*  inertia= (const float*)d_in[3];
    const float*  damping= (const float*)d_in[4];

    float* out    = (float*)d_out;                       // (B,T,8)
    float* muscle = out + (size_t)NB * TS * NJ;          // (B,8,2,2)
    float* finals = muscle + (size_t)NB * NJ * 2 * 2;    // (B,8,2)

    dim3 block(256);          // 4 waves = 4 joints (half batch)
    dim3 grid(NB * 2);        // 2048 half-blocks; siblings 8 apart (same XCD)
    phys_half_kernel<<<grid, block, 0, stream>>>(x, state0, M, inertia, damping,
                                                 out, muscle, finals);
}

// Round 10
// 72.237 us; speedup vs baseline: 1.2489x; 1.0164x over previous
//
#include <hip/hip_runtime.h>

#define NJ 8
#define TS 2048
#define NB 1024
#define JW 4                    // joints per half-block
#define CHUNK 256               // 64 lanes * 4 steps per wave-scan
#define NCH (TS / CHUNK)        // 8
#define F4C (CHUNK * JW)        // 1024 float4 = 16 KB per buffer
#define DTC (1.0f / 60.0f)

// async global->LDS, 16B per lane. lds_base must be wave-uniform; HW writes
// lds_base + lane*16. Global src is per-lane.
__device__ __forceinline__ void dma16(const float4* g, float4* lds_base) {
#if __has_builtin(__builtin_amdgcn_global_load_lds)
    __builtin_amdgcn_global_load_lds(
        (const __attribute__((address_space(1))) void*)g,
        (__attribute__((address_space(3))) void*)lds_base,
        16, 0, 0);
#else
    lds_base[threadIdx.x & 63] = *g;
#endif
}

// DPP cross-lane move, all-VALU (no DS pipe). CTRL: row_shr:N = 0x110+N,
// row_bcast15 = 0x142, row_bcast31 = 0x143. Invalid-source lanes keep v
// (old = v, bound_ctrl = false) — we guard those lanes anyway.
template<int CTRL>
__device__ __forceinline__ float dppf(float v) {
    return __int_as_float(__builtin_amdgcn_update_dpp(
        __float_as_int(v), __float_as_int(v), CTRL, 0xF, 0xF, false));
}

#define ROUND(CTRL, COND) do {                                          \
    float o_r0 = dppf<CTRL>(r0), o_r1 = dppf<CTRL>(r1),                 \
          o_rc = dppf<CTRL>(rc), o_s0 = dppf<CTRL>(s0),                 \
          o_s1 = dppf<CTRL>(s1), o_sc = dppf<CTRL>(sc);                 \
    if (COND) {                                                         \
        float nr0 = fmaf(r0, o_s0, r1 * o_r0);                          \
        float nr1 = fmaf(r0, o_s1, r1 * o_r1);                          \
        float nrc = fmaf(r0, o_sc, fmaf(r1, o_rc, rc));                 \
        float ns0 = fmaf(s0, o_s0, s1 * o_r0);                          \
        float ns1 = fmaf(s0, o_s1, s1 * o_r1);                          \
        float nsc = fmaf(s0, o_sc, fmaf(s1, o_rc, sc));                 \
        r0 = nr0; r1 = nr1; rc = nrc; s0 = ns0; s1 = ns1; sc = nsc;     \
    } } while (0)

__global__ __launch_bounds__(256, 4) void phys_dpp_kernel(
    const float4* __restrict__ x,       // (B,T,8) as float4 per (t,joint)
    const float*  __restrict__ state0,  // (B,8,2)
    const float*  __restrict__ M,       // (8,2)
    const float*  __restrict__ inertia, // (8,)
    const float*  __restrict__ damping, // (8,)
    float* __restrict__ out,            // (B,T,8)
    float* __restrict__ muscle,         // (B,8,2,2)
    float* __restrict__ finals)         // (B,8,2)
{
    __shared__ float4 xin[2][F4C];           // 2 x 16 KB input double-buffer
    __shared__ float4 tb[2][CHUNK * JW / 4]; // 2 x 4 KB theta transpose dbuf

    // sibling half-blocks (same batch) differ by 8 in blockIdx -> same XCD,
    // dispatched back-to-back -> partial output lines merge in shared L2.
    const int g   = blockIdx.x;
    const int b   = (g & 7) | ((g >> 4) << 3);
    const int J0  = ((g >> 3) & 1) * JW;

    const int tid  = threadIdx.x;
    const int w    = tid >> 6;          // wave id = joint offset in half
    const int lane = tid & 63;
    const int j    = J0 + w;

    const float M0  = M[j * 2 + 0];
    const float M1  = M[j * 2 + 1];
    const float M20 = M0 * M0;
    const float M21 = M1 * M1;
    const float d   = damping[j];
    const float p   = DTC / inertia[j];      // DT / I
    const float gd  = 1.0f - p * d;          // dθ self-coefficient

    float thc  = state0[(b * NJ + j) * 2 + 0];
    float dthc = state0[(b * NJ + j) * 2 + 1];

    const float4* xb = x + (size_t)b * TS * NJ;

    // xin layout: natural n = 4*t_local + jl; stored at sigma(n) = n^((n>>4)&7)
    // (involution). DMA dest linear dd = 256w+64i+lane; global element
    // n = sigma(dd). Each dma16 covers 16 full 64-B half-rows (dense).
    auto issue = [&](int ch, float4* bb) {
        const int T0 = ch * CHUNK;
        #pragma unroll
        for (int i = 0; i < 4; ++i) {
            int dd = 256 * w + 64 * i + lane;
            int n  = dd ^ ((dd >> 4) & 7);
            const float4* src = xb + (size_t)(T0 + (n >> 2)) * NJ + J0 + (n & 3);
            dma16(src, bb + 256 * w + 64 * i);
        }
    };

    // prologue: async-stage chunk 0
    issue(0, xin[0]);

    for (int ch = 0; ch <= NCH; ++ch) {
        // single barrier per chunk: drains DMA(ch) [vmcnt] and makes
        // tout(ch-1) visible [lgkmcnt]; also buffer-overwrite safety.
        __syncthreads();

        // issue DMA for chunk ch+1 into the other xin buffer (full-chunk slack)
        if (ch + 1 < NCH) issue(ch + 1, xin[(ch + 1) & 1]);

        // ---- store phase: coalesced write-out of chunk ch-1's theta ----
        if (ch > 0) {
            const float4* tr = tb[(ch - 1) & 1];
            int f  = tid;                       // 0..255
            int q  = f ^ ((f >> 5) & 7);
            int pm = (f >> 3) & 3;
            float4 r = tr[q];
            float rx = r.x, ry = r.y, rz = r.z, rw = r.w;
            if (pm & 1) { float tq = rx; rx = ry; ry = tq; tq = rz; rz = rw; rw = tq; }
            if (pm & 2) { float tq = rx; rx = rz; rz = tq; tq = ry; ry = rw; rw = tq; }
            float4* og = (float4*)out
                       + 2 * ((size_t)b * TS + (size_t)(ch - 1) * CHUNK + f)
                       + (J0 >> 2);
            *og = make_float4(rx, ry, rz, rw);
        }

        if (ch < NCH) {
            // ---- compute phase on xin[ch&1] ----
            const float4* xc = xin[ch & 1];
            float* tw = (float*)tb[ch & 1];

            // element (step 4*lane+k, joint w): natural n = 16*lane + 4k + w,
            // read at n ^ ((n>>4)&7) = n ^ (lane&7)  -> conflict-free b128
            float a[4], cc[4];
            const int bm = lane & 7;
            #pragma unroll
            for (int k = 0; k < 4; ++k) {
                int n = 16 * lane + 4 * k + w;
                float4 v = xc[n ^ bm];
                a[k]  = fmaf(M0,  v.x, M1  * v.y);   // einsum(M, F_t)
                cc[k] = fmaf(M20, v.z, M21 * v.w);   // einsum(M2, K_t)
            }

            // serially compose my 4 step-maps:
            //   dθ' = r0·θ + r1·dθ + rc ;  θ' = s0·θ + s1·dθ + sc
            float r0 = 0.0f, r1 = 1.0f, rc = 0.0f;   // identity
            float s0 = 1.0f, s1 = 0.0f, sc = 0.0f;
            #pragma unroll
            for (int k = 0; k < 4; ++k) {
                float pa = p * a[k];
                float pc = p * cc[k];
                float nr0 = fmaf(-pc, s0, gd * r0);
                float nr1 = fmaf(-pc, s1, gd * r1);
                float nrc = fmaf(-pc, sc, fmaf(gd, rc, pa));
                s0 = fmaf(DTC, nr0, s0);
                s1 = fmaf(DTC, nr1, s1);
                sc = fmaf(DTC, nrc, sc);
                r0 = nr0; r1 = nr1; rc = nrc;
            }

            // inclusive scan over 64 lanes — canonical GCN DPP wave-scan,
            // all VALU (zero DS-pipe ops): row_shr 1/2/4/8 within 16-lane
            // rows, then row_bcast15 (rows 1,3 <- lanes 15/47), then
            // row_bcast31 (lanes >=32 <- lane 31).
            ROUND(0x111, (lane & 15) >= 1);
            ROUND(0x112, (lane & 15) >= 2);
            ROUND(0x114, (lane & 15) >= 4);
            ROUND(0x118, (lane & 15) >= 8);
            ROUND(0x142, (lane & 31) >= 16);
            ROUND(0x143, lane >= 32);

            // end state after my steps = inclusive map applied to carry;
            // my start state = lane (l-1)'s end state (bit-identical to the
            // old exclusive-map formulation), shifted up by 1.
            float th_e  = fmaf(s0, thc, fmaf(s1, dthc, sc));
            float dth_e = fmaf(r0, thc, fmaf(r1, dthc, rc));
            float th  = __shfl_up(th_e, 1, 64);
            float dth = __shfl_up(dth_e, 1, 64);
            if (lane == 0) { th = thc; dth = dthc; }

            // replay 4 steps in exact reference op-order; θ -> transpose buf.
            // word wd = 16*lane + 4k + w; store at wd ^ ((wd>>5)&31)
            //         = wd ^ ((lane>>1)&31)   (2 lanes/bank = free)
            const int wsig = (lane >> 1) & 31;
            #pragma unroll
            for (int k = 0; k < 4; ++k) {
                float u = fmaf(-cc[k], th, a[k]);    // a - c·θ
                u = fmaf(-d, dth, u);                // ... - d·dθ
                dth = fmaf(p, u, dth);
                th  = fmaf(DTC, dth, th);
                tw[(16 * lane + 4 * k + w) ^ wsig] = th;
            }

            // carry = lane 63's end state (uniform lane -> v_readlane)
            thc  = __shfl(th, 63, 64);
            dthc = __shfl(dth, 63, 64);
        }
    }

    if (lane == 0) {
        const int idx = b * NJ + j;
        finals[idx * 2 + 0] = thc;
        finals[idx * 2 + 1] = dthc;
        muscle[idx * 4 + 0] = thc  * M0;
        muscle[idx * 4 + 1] = thc  * M1;
        muscle[idx * 4 + 2] = dthc * M0;
        muscle[idx * 4 + 3] = dthc * M1;
    }
}

extern "C" void kernel_launch(void* const* d_in, const int* in_sizes, int n_in,
                              void* d_out, int out_size, void* d_ws, size_t ws_size,
                              hipStream_t stream) {
    const float4* x      = (const float4*)d_in[0];
    const float*  state0 = (const float*)d_in[1];
    const float*  M      = (const float*)d_in[2];
    const float*  inertia= (const float*)d_in[3];
    const float*  damping= (const float*)d_in[4];

    float* out    = (float*)d_out;                       // (B,T,8)
    float* muscle = out + (size_t)NB * TS * NJ;          // (B,8,2,2)
    float* finals = muscle + (size_t)NB * NJ * 2 * 2;    // (B,8,2)

    dim3 block(256);          // 4 waves = 4 joints (half batch)
    dim3 grid(NB * 2);        // 2048 half-blocks; siblings 8 apart (same XCD)
    phys_dpp_kernel<<<grid, block, 0, stream>>>(x, state0, M, inertia, damping,
                                                out, muscle, finals);
}